// Round 11
// baseline (1969.879 us; speedup 1.0000x reference)
//
#include <hip/hip_runtime.h>
#include <hip/hip_bf16.h>
#include <stdint.h>

// ---------------- problem constants (fixed by setup_inputs) ----------------
#define DIMC   4096
#define HC     32
#define DC     128
#define TPC    2048      // prefill tokens
#define TOKC   2056      // total tokens
#define BDC    8         // decode batch
#define MAXBC  64        // blocks per decode seq
#define PSEQC  1024      // prefill seq len (2 seqs)
#define QKVN   12288     // 3*H*D
#define FFNC   16384     // 4*DIM
#define PSCALE 0.08838834764831843f  // 1/sqrt(128)

typedef __attribute__((ext_vector_type(8))) short short8;
typedef __attribute__((ext_vector_type(4))) float f32x4;
typedef __attribute__((ext_vector_type(4))) unsigned short u16x4;
typedef __attribute__((ext_vector_type(8))) unsigned short u16x8;

__device__ inline unsigned short f2bf(float f) {   // f32 -> bf16 RNE
  union { float f; unsigned u; } v; v.f = f;
  unsigned r = v.u + 0x7FFFu + ((v.u >> 16) & 1u);
  return (unsigned short)(r >> 16);
}
__device__ inline float bf2f(unsigned short u) {
  union { unsigned u; float f; } v; v.u = ((unsigned)u) << 16;
  return v.f;
}
__device__ inline f32x4 mfma16(short8 a, short8 b, f32x4 c) {
  return __builtin_amdgcn_mfma_f32_16x16x32_bf16(a, b, c, 0, 0, 0);
}
__device__ inline void gload16(const void* g, void* l) {
  __builtin_amdgcn_global_load_lds(
      (const __attribute__((address_space(1))) void*)g,
      (__attribute__((address_space(3))) void*)l, 16, 0, 0);
}

// ---------------- weight convert f32 -> bf16 (standalone: wqkv only) -------
__global__ __launch_bounds__(256) void cvt_w(
    const float* __restrict__ in, unsigned short* __restrict__ out, long n8)
{
  long i = (long)blockIdx.x * 256 + threadIdx.x;
  const long stride = (long)gridDim.x * 256;
  for (; i < n8; i += stride) {
    f32x4 a = ((const f32x4*)in)[2 * i];
    f32x4 b = ((const f32x4*)in)[2 * i + 1];
    u16x8 o;
#pragma unroll
    for (int j = 0; j < 4; ++j) { o[j] = f2bf(a[j]); o[j + 4] = f2bf(b[j]); }
    ((u16x8*)out)[i] = o;
  }
}

// ---------------- RMSNorm: f32 in -> bf16 out ----------------
__global__ __launch_bounds__(256) void rmsnorm_k(
    const float* __restrict__ x, const float* __restrict__ w,
    unsigned short* __restrict__ out)
{
  const int row = blockIdx.x;
  const int tid = threadIdx.x;
  const f32x4* xr = (const f32x4*)(x + (size_t)row * DIMC);
  f32x4 v[4];
  float ss = 0.f;
#pragma unroll
  for (int i = 0; i < 4; ++i) {
    v[i] = xr[i * 256 + tid];
    ss += v[i][0]*v[i][0] + v[i][1]*v[i][1] + v[i][2]*v[i][2] + v[i][3]*v[i][3];
  }
  for (int off = 32; off; off >>= 1) ss += __shfl_xor(ss, off);
  __shared__ float sred[4];
  if ((tid & 63) == 0) sred[tid >> 6] = ss;
  __syncthreads();
  const float rms = rsqrtf((sred[0]+sred[1]+sred[2]+sred[3]) * (1.f/DIMC) + 1e-5f);
  const f32x4* wr = (const f32x4*)w;
#pragma unroll
  for (int i = 0; i < 4; ++i) {
    f32x4 wv = wr[i * 256 + tid];
    u16x4 o;
#pragma unroll
    for (int j = 0; j < 4; ++j) o[j] = f2bf(v[i][j] * rms * wv[j]);
    *(u16x4*)(out + (size_t)row * DIMC + (size_t)(i * 256 + tid) * 4) = o;
  }
}

// ============ pipelined 256x256 GEMM (T2+T3+T4+T5), bf16 B ============
// EXACT R8 K-loop schedule (measured best: gu 527us, 52% MfmaUtil, no spill).
// C[M,N] = A_bf16[M,K] @ B_bf16[N,K]^T (+Res).
// MODE 1: f32 out + Res; MODE 2: bf16 out; MODE 3: f32 split-K partial;
// MODE 4: fused SiLU-pair epilogue (B = 16-col-interleaved wgu_perm; frag n=0
//         holds g, n=1 holds u in the SAME lane; writes act[M, N/2] bf16).
// CO-RUN CVT: blocks with wgid >= tilesTotal do grid-stride f32->bf16 weight
// conversion (job1 optionally row-PERMUTED for wgu, then job2 plain). These
// are the highest blockIdx values (monotone XCD chunking, nwg%8==0) ->
// scheduled last -> fill GEMM tail rounds with otherwise-idle CUs.
template<int MODE, int SK>
__global__ __launch_bounds__(512, 2) void gemm8p(
    const unsigned short* __restrict__ A, const unsigned short* __restrict__ Bh,
    float* __restrict__ Cf, unsigned short* __restrict__ Cb,
    const float* __restrict__ Res, int M, int N, int K,
    const float* cv1In, unsigned short* cv1Out, long cv1N8, int cv1Perm,
    const float* cv2In, unsigned short* cv2Out, long cv2N8)
{
  __shared__ char ldsc[131072];
  const int tid = threadIdx.x;
  const int lane = tid & 63, wid = tid >> 6;
  const int wr = wid >> 2, wc = wid & 3;
  const int lhi = lane >> 4, llo = lane & 15;

  // bijective XCD chunking over the whole grid, then (ks, bn, bm) M-fast
  const int nM = (M + 255) >> 8;
  const int nN = N >> 8;
  const int nwg = gridDim.x, orig = blockIdx.x;
  const int qq = nwg >> 3, rr = nwg & 7;
  const int xcd = orig & 7, lid = orig >> 3;
  const int wgid = (xcd < rr ? xcd*(qq+1) : rr*(qq+1) + (xcd-rr)*qq) + lid;
  const int tilesTotal = nM * nN * SK;

  // -------- co-run weight conversion (tail blocks) --------
  if (wgid >= tilesTotal) {
    const long cid = wgid - tilesTotal;
    const long CVB = (long)nwg - tilesTotal;
    const long tot = cv1N8 + cv2N8;
    for (long i = cid * 512 + tid; i < tot; i += CVB * 512) {
      if (i < cv1N8) {
        long e8 = i;
        long srcE8;
        if (cv1Perm) {
          // wgu 16-col interleave: out row r2 (len 4096 = 512 chunks);
          // b=r2>>5, off=r2&31; src = off<16 ? b*16+off : 16384+b*16+(off&15)
          long r2 = e8 >> 9, c8 = e8 & 511;
          long b = r2 >> 5, off = r2 & 31;
          long srcr = (off < 16) ? (b * 16 + off) : (16384 + b * 16 + (off & 15));
          srcE8 = srcr * 512 + c8;
        } else {
          srcE8 = e8;
        }
        f32x4 a = ((const f32x4*)cv1In)[2 * srcE8];
        f32x4 b2 = ((const f32x4*)cv1In)[2 * srcE8 + 1];
        u16x8 o;
#pragma unroll
        for (int j = 0; j < 4; ++j) { o[j] = f2bf(a[j]); o[j + 4] = f2bf(b2[j]); }
        ((u16x8*)cv1Out)[e8] = o;
      } else {
        long e8 = i - cv1N8;
        f32x4 a = ((const f32x4*)cv2In)[2 * e8];
        f32x4 b2 = ((const f32x4*)cv2In)[2 * e8 + 1];
        u16x8 o;
#pragma unroll
        for (int j = 0; j < 4; ++j) { o[j] = f2bf(a[j]); o[j + 4] = f2bf(b2[j]); }
        ((u16x8*)cv2Out)[e8] = o;
      }
    }
    return;
  }

  const int ks = wgid / (nM * nN);
  const int tile = wgid % (nM * nN);
  const int bm = (tile % nM) << 8;
  const int bn = (tile / nM) << 8;
  const int kLen = K / SK;
  const int k0 = ks * kLen;
  const int NT = kLen >> 6;   // >= 4, even, for all our shapes

  // staging sources: slot s=i*512+tid -> row=s>>3, stored chunk (s&7),
  // holding logical chunk (s&7)^(row&7)  (read-side XOR matches)
  const unsigned short* src[2][2][2];  // [op A/B][half][issue]
#pragma unroll
  for (int i = 0; i < 2; ++i) {
    int s = i * 512 + tid;
    int row = s >> 3;
    int chunk = (s & 7) ^ (row & 7);
#pragma unroll
    for (int h = 0; h < 2; ++h) {
      int ga = bm + h * 128 + row; ga = ga < M ? ga : M - 1;
      src[0][h][i] = A  + (size_t)ga * K + k0 + chunk * 8;
      src[1][h][i] = Bh + (size_t)(bn + h * 128 + row) * K + k0 + chunk * 8;
    }
  }

#define STG(U, OP, H) do { \
    int bb_ = (((U) & 1) << 16) + ((OP) << 15) + ((H) << 14) + (wid << 10); \
    gload16(src[OP][H][0] + ((size_t)(U) << 6), ldsc + bb_); \
    gload16(src[OP][H][1] + ((size_t)(U) << 6), ldsc + bb_ + 8192); \
  } while (0)

#define LDA(PB, HA) do { _Pragma("unroll") for (int m_ = 0; m_ < 4; ++m_) { \
    int row_ = wr*64 + m_*16 + llo; \
    int rb_ = (PB) + ((HA) << 14) + row_*128; int sx_ = (row_ & 7) << 4; \
    ar[m_][0] = *(const short8*)(ldsc + rb_ + ((lhi*16) ^ sx_)); \
    ar[m_][1] = *(const short8*)(ldsc + rb_ + ((64 + lhi*16) ^ sx_)); } } while (0)

#define LDB(PB, HB, DST) do { _Pragma("unroll") for (int n_ = 0; n_ < 2; ++n_) { \
    int row_ = wc*32 + n_*16 + llo; \
    int rb_ = (PB) + 32768 + ((HB) << 14) + row_*128; int sx_ = (row_ & 7) << 4; \
    DST[n_][0] = *(const short8*)(ldsc + rb_ + ((lhi*16) ^ sx_)); \
    DST[n_][1] = *(const short8*)(ldsc + rb_ + ((64 + lhi*16) ^ sx_)); } } while (0)

#define MM(QA, QB, B_) do { __builtin_amdgcn_s_setprio(1); \
    _Pragma("unroll") for (int m_ = 0; m_ < 4; ++m_) \
    _Pragma("unroll") for (int n_ = 0; n_ < 2; ++n_) { \
      acc[QA][QB][m_][n_] = mfma16(ar[m_][0], B_[n_][0], acc[QA][QB][m_][n_]); \
      acc[QA][QB][m_][n_] = mfma16(ar[m_][1], B_[n_][1], acc[QA][QB][m_][n_]); } \
    __builtin_amdgcn_s_setprio(0); } while (0)

#define FEN __builtin_amdgcn_sched_barrier(0)
#define BAR __builtin_amdgcn_s_barrier()
#define VMB(N) do { FEN; asm volatile("s_waitcnt vmcnt(" #N ")" ::: "memory"); \
    BAR; FEN; } while (0)

  f32x4 acc[2][2][4][2] = {};
  short8 ar[4][2], b0[2][2], b1[2][2];

  // prologue: t0 {A0,B0,B1,A1} + t1 {A0,B0,B1} = 14 loads; vmcnt(6) lands
  // all of t0, leaves t1{A0,B0,B1}=6 (steady entry invariant); preload frags.
  STG(0, 0, 0); STG(0, 1, 0); STG(0, 1, 1); STG(0, 0, 1);
  STG(1, 0, 0); STG(1, 1, 0); STG(1, 1, 1);
  VMB(6);
  LDA(0, 0); LDB(0, 0, b0);

  for (int t = 0; t < NT - 2; ++t) {
    const int pb = (t & 1) << 16, pbn = ((t + 1) & 1) << 16;
    // q0
    LDB(pb, 1, b1);
    STG(t + 1, 0, 1);
    MM(0, 0, b0);
    BAR;
    // q1
    STG(t + 2, 0, 0);
    MM(0, 1, b1);
    LDA(pb, 1);            // ar <- A1(t), after MM(0,1) read A0 (reg WAR)
    BAR;
    // q2
    STG(t + 2, 1, 0);
    MM(1, 1, b1);
    VMB(8);                // lands t+1{A0,B0} -> q3 may read them
    // q3
    STG(t + 2, 1, 1);
    MM(1, 0, b0);
    LDA(pbn, 0);           // ar <- A0(t+1)
    LDB(pbn, 0, b0);       // b0 <- B0(t+1)
    VMB(6);                // lands t+1{B1,A1}
  }
  // tile NT-2: no t+2 stages; exact tail waits 4,0
  {
    const int pb = ((NT - 2) & 1) << 16, pbn = ((NT - 1) & 1) << 16;
    LDB(pb, 1, b1);
    STG(NT - 1, 0, 1);
    MM(0, 0, b0);
    BAR;
    MM(0, 1, b1);
    LDA(pb, 1);
    BAR;
    MM(1, 1, b1);
    VMB(4);                // lands (NT-1){A0,B0}
    MM(1, 0, b0);
    LDA(pbn, 0);
    LDB(pbn, 0, b0);
    VMB(0);                // lands (NT-1){B1,A1}
  }
  // tile NT-1: barrier-free drain (no stores pending, all data landed)
  {
    const int pb = ((NT - 1) & 1) << 16;
    LDB(pb, 1, b1);
    MM(0, 0, b0);
    MM(0, 1, b1);
    LDA(pb, 1);
    MM(1, 1, b1);
    MM(1, 0, b0);
  }

  // epilogue: C/D layout col=lane&15, row=(lane>>4)*4+j
  float* Pf = (MODE == 3) ? (Cf + (size_t)ks * M * N) : Cf;
#pragma unroll
  for (int qa = 0; qa < 2; ++qa)
#pragma unroll
  for (int m_ = 0; m_ < 4; ++m_)
#pragma unroll
  for (int j = 0; j < 4; ++j) {
    int row = bm + qa*128 + wr*64 + m_*16 + lhi*4 + j;
    if (row < M) {
      if (MODE == 4) {
        // frag n=0 = g (cols base..base+15), n=1 = u (base+16..base+31),
        // same lane; act col = base/2 + llo, act ld = N/2.
#pragma unroll
        for (int qb = 0; qb < 2; ++qb) {
          int base = bn + qb*128 + wc*32;
          float g = acc[qa][qb][m_][0][j];
          float u = acc[qa][qb][m_][1][j];
          float sv = g / (1.f + __expf(-g)) * u;
          Cb[(size_t)row * (N >> 1) + (base >> 1) + llo] = f2bf(sv);
        }
      } else {
#pragma unroll
        for (int qb = 0; qb < 2; ++qb)
#pragma unroll
        for (int n_ = 0; n_ < 2; ++n_) {
          int col = bn + qb*128 + wc*32 + n_*16 + llo;
          float v = acc[qa][qb][m_][n_][j];
          if (MODE == 1) { v += Res[(size_t)row*N + col]; Pf[(size_t)row*N + col] = v; }
          else if (MODE == 3) { Pf[(size_t)row*N + col] = v; }
          else Cb[(size_t)row*N + col] = f2bf(v);
        }
      }
    }
  }
#undef STG
#undef LDA
#undef LDB
#undef MM
#undef FEN
#undef BAR
#undef VMB
}

// ---------------- split-K reduce: out = p0+p1+p2+p3 + res ----------------
__global__ __launch_bounds__(256) void redk(
    const float* __restrict__ p, const float* __restrict__ res,
    float* __restrict__ out, long n4)
{
  long i = (long)blockIdx.x * 256 + threadIdx.x;
  if (i >= n4) return;
  const f32x4* p4 = (const f32x4*)p;
  f32x4 v = p4[i] + p4[i + n4] + p4[i + 2*n4] + p4[i + 3*n4]
          + ((const f32x4*)res)[i];
  ((f32x4*)out)[i] = v;
}

// ---------------- 128x128 2-barrier GEMM (kept for wo + f32 fallback) -------
template<int MODE, int BF16B>
__global__ __launch_bounds__(256) void gemm_bt(
    const unsigned short* __restrict__ A, const float* __restrict__ Bf,
    const unsigned short* __restrict__ Bh,
    float* __restrict__ Cf, unsigned short* __restrict__ Cb,
    const float* __restrict__ Res, int M, int N, int K)
{
  __shared__ unsigned short la[128 * 64];
  __shared__ unsigned short lb[128 * 64];
  const int tid = threadIdx.x;
  const int lane = tid & 63, wid = tid >> 6;
  const int wr = wid >> 1, wc = wid & 1;
  const int lhi = lane >> 4, llo = lane & 15;

  const int nM = (M + 127) >> 7;
  const int nwg = gridDim.x;
  const int orig = blockIdx.x;
  const int qq = nwg >> 3, rr = nwg & 7;
  const int xcd = orig & 7, lid = orig >> 3;
  const int wgid = (xcd < rr ? xcd * (qq + 1) : rr * (qq + 1) + (xcd - rr) * qq) + lid;
  const int bm = (wgid % nM) * 128;
  const int bn = (wgid / nM) * 128;

  const unsigned short* aSrc[4];
  const unsigned short* bSrcH[4];
  char* aDst[4];
  char* bDst[4];
#pragma unroll
  for (int p = 0; p < 4; ++p) {
    int slot = p * 256 + tid;
    int row = slot >> 3;
    int chunk = (slot & 7) ^ (row & 7);
    int gr = bm + row; gr = gr < M ? gr : M - 1;
    aSrc[p] = A + (size_t)gr * K + chunk * 8;
    aDst[p] = (char*)la + p * 4096 + wid * 1024;
    if (BF16B) {
      bSrcH[p] = Bh + (size_t)(bn + row) * K + chunk * 8;
      bDst[p] = (char*)lb + p * 4096 + wid * 1024;
    }
  }

  f32x4 acc[4][4] = {};

  for (int k0 = 0; k0 < K; k0 += 64) {
#pragma unroll
    for (int p = 0; p < 4; ++p) gload16(aSrc[p] + k0, aDst[p]);
    if (BF16B) {
#pragma unroll
      for (int p = 0; p < 4; ++p) gload16(bSrcH[p] + k0, bDst[p]);
    } else {
#pragma unroll
      for (int p = 0; p < 4; ++p) {
        int idx = p * 256 + tid;
        int row = idx >> 3, c8 = (idx & 7) << 3;
        const float* srcf = Bf + (size_t)(bn + row) * K + k0 + c8;
        f32x4 v0 = *(const f32x4*)srcf;
        f32x4 v1 = *(const f32x4*)(srcf + 4);
        short8 bv;
#pragma unroll
        for (int i = 0; i < 4; ++i) { bv[i] = (short)f2bf(v0[i]); bv[i+4] = (short)f2bf(v1[i]); }
        int byt = (row << 7) + (c8 << 1);
        byt ^= (row & 7) << 4;
        *(short8*)((char*)lb + byt) = bv;
      }
    }
    __syncthreads();
#pragma unroll
    for (int kk = 0; kk < 64; kk += 32) {
      short8 af[4], bfr[4];
#pragma unroll
      for (int m = 0; m < 4; ++m) {
        int row = wr * 64 + m * 16 + llo;
        int byt = (row << 7) + ((kk + lhi * 8) << 1);
        byt ^= (row & 7) << 4;
        af[m] = *(const short8*)((const char*)la + byt);
      }
#pragma unroll
      for (int n = 0; n < 4; ++n) {
        int row = wc * 64 + n * 16 + llo;
        int byt = (row << 7) + ((kk + lhi * 8) << 1);
        byt ^= (row & 7) << 4;
        bfr[n] = *(const short8*)((const char*)lb + byt);
      }
#pragma unroll
      for (int m = 0; m < 4; ++m)
#pragma unroll
        for (int n = 0; n < 4; ++n)
          acc[m][n] = mfma16(af[m], bfr[n], acc[m][n]);
    }
    __syncthreads();
  }

#pragma unroll
  for (int m = 0; m < 4; ++m) {
#pragma unroll
    for (int j = 0; j < 4; ++j) {
      int row = bm + wr * 64 + m * 16 + lhi * 4 + j;
      if (row < M) {
#pragma unroll
        for (int n = 0; n < 4; ++n) {
          int col = bn + wc * 64 + n * 16 + llo;
          float v = acc[m][n][j];
          if (MODE == 1) {
            v += Res[(size_t)row * N + col];
            Cf[(size_t)row * N + col] = v;
          } else {
            Cb[(size_t)row * N + col] = f2bf(v);
          }
        }
      }
    }
  }
}

// ---------------- Prefill flash attention (causal, per-seq) ----------------
// 512 thr = 8 waves x 16 q-rows = 128 q-rows/block.  K staged via
// global_load_lds w/ pre-swizzled source; V^T staged with paired u32 writes;
// waves above the diagonal skip compute (wave-uniform guard).
__global__ __launch_bounds__(512) void prefill_attn(
    const unsigned short* __restrict__ qkv, unsigned short* __restrict__ attnb)
{
  const int h = blockIdx.x, qtb = blockIdx.y, s = blockIdx.z;
  const int seq0 = s * PSEQC;
  const int q0 = qtb * 128;
  const int tid = threadIdx.x;
  const int lane = tid & 63, w = tid >> 6;
  const int lhi = lane >> 4, llo = lane & 15;
  const int qw = q0 + w * 16;          // wave's rows qw..qw+15

  __shared__ unsigned short lk[64 * 128];
  __shared__ unsigned short lvt[128 * 72];
  __shared__ unsigned short lp[8][16 * 72];

  short8 qf[4];
  {
    const unsigned short* qrow =
        qkv + (size_t)(seq0 + qw + llo) * QKVN + h * DC;
#pragma unroll
    for (int kk = 0; kk < 4; ++kk)
      qf[kk] = *(const short8*)(qrow + kk * 32 + lhi * 8);
  }

  float m_r[4], l_r[4];
#pragma unroll
  for (int r = 0; r < 4; ++r) { m_r[r] = -1e30f; l_r[r] = 0.f; }
  f32x4 oacc[8] = {};

  const int ntiles = 2 * qtb + 2;
  for (int t = 0; t < ntiles; ++t) {
    const int j0 = t * 64;
#pragma unroll
    for (int p = 0; p < 2; ++p) {
      int idx = p * 512 + tid;
      int row = idx >> 4, cs = idx & 15;
      int cg = cs ^ (row & 7);
      gload16(qkv + (size_t)(seq0 + j0 + row) * QKVN + DIMC + h * DC + cg * 8,
              (char*)lk + p * 8192 + w * 1024);
    }
    {
      int jp = tid >> 4;            // 0..31
      int c8 = (tid & 15) << 3;
      int j = jp * 2;
      const unsigned short* vrow =
          qkv + (size_t)(seq0 + j0 + j) * QKVN + 2 * DIMC + h * DC + c8;
      short8 v0 = *(const short8*)vrow;
      short8 v1 = *(const short8*)(vrow + QKVN);
#pragma unroll
      for (int i = 0; i < 8; ++i) {
        int d = c8 + i;
        int jj = j ^ (((d >> 3) & 7) << 3);
        unsigned pack = (unsigned)(unsigned short)v0[i]
                      | ((unsigned)(unsigned short)v1[i] << 16);
        *(unsigned*)(lvt + d * 72 + jj) = pack;
      }
    }
    asm volatile("s_waitcnt vmcnt(0)" ::: "memory");
    __syncthreads();

    const bool active = (j0 <= qw + 15);   // wave-uniform
    if (active) {
      f32x4 sfr[4] = {};
#pragma unroll
      for (int n = 0; n < 4; ++n) {
        int row = n * 16 + llo;
#pragma unroll
        for (int kk = 0; kk < 4; ++kk) {
          int col = (kk * 32 + lhi * 8) ^ ((row & 7) << 3);
          short8 kf = *(const short8*)(lk + row * 128 + col);
          sfr[n] = mfma16(qf[kk], kf, sfr[n]);
        }
      }

      const bool diag = (j0 + 63 > qw);
      const int qbase = qw + lhi * 4;
      float pv[4][4];
#pragma unroll
      for (int r = 0; r < 4; ++r) {
        float mx = -1e30f;
#pragma unroll
        for (int n = 0; n < 4; ++n) {
          float sv = sfr[n][r] * PSCALE;
          if (diag && (j0 + n * 16 + llo > qbase + r)) sv = -1e30f;
          pv[n][r] = sv;
          mx = fmaxf(mx, sv);
        }
        for (int off = 8; off; off >>= 1) mx = fmaxf(mx, __shfl_xor(mx, off));
        float mnew = fmaxf(m_r[r], mx);
        float alpha = __expf(m_r[r] - mnew);
        m_r[r] = mnew;
        float rs = 0.f;
#pragma unroll
        for (int n = 0; n < 4; ++n) {
          float p = __expf(pv[n][r] - mnew);
          pv[n][r] = p;
          rs += p;
        }
        for (int off = 8; off; off >>= 1) rs += __shfl_xor(rs, off);
        l_r[r] = l_r[r] * alpha + rs;
#pragma unroll
        for (int f = 0; f < 8; ++f) oacc[f][r] *= alpha;
      }

      unsigned short* lpw = lp[w];
#pragma unroll
      for (int r = 0; r < 4; ++r)
#pragma unroll
        for (int n = 0; n < 4; ++n)
          lpw[(lhi * 4 + r) * 72 + n * 16 + llo] = f2bf(pv[n][r]);

#pragma unroll
      for (int kk = 0; kk < 2; ++kk) {
        short8 pf = *(const short8*)(lpw + llo * 72 + kk * 32 + lhi * 8);
#pragma unroll
        for (int f = 0; f < 8; ++f) {
          int d = f * 16 + llo;
          int jb = kk * 32 + lhi * 8;
          int jj = jb ^ (((d >> 3) & 7) << 3);
          short8 vf = *(const short8*)(lvt + d * 72 + jj);
          oacc[f] = mfma16(pf, vf, oacc[f]);
        }
      }
    }
    __syncthreads();
  }

#pragma unroll
  for (int r = 0; r < 4; ++r) {
    int row = seq0 + qw + lhi * 4 + r;
    float inv = 1.f / l_r[r];
#pragma unroll
    for (int f = 0; f < 8; ++f)
      attnb[(size_t)row * DIMC + h * DC + f * 16 + llo] = f2bf(oacc[f][r] * inv);
  }
}

// ---------------- Decode attention (paged KV, fresh-kv override) ------------
__global__ __launch_bounds__(256) void decode_attn(
    const unsigned short* __restrict__ qkv,
    const float* __restrict__ kheap, const float* __restrict__ vheap,
    const int* __restrict__ btab, const int* __restrict__ ctxl,
    unsigned short* __restrict__ attnb)
{
  const int h = blockIdx.x, b = blockIdx.y;
  const int ctx = ctxl[b];
  const int tq = TPC + b;
  const int tid = threadIdx.x;
  __shared__ float sq[DC];
  __shared__ float sp[1024];
  __shared__ float sred[4];
  __shared__ float obuf[DC];

  const unsigned short* qrow = qkv + (size_t)tq * QKVN + h * DC;
  if (tid < DC) sq[tid] = bf2f(qrow[tid]);
  __syncthreads();

  float lmax = -1e30f;
#pragma unroll
  for (int i = 0; i < 4; ++i) {
    int l = i * 256 + tid;
    float sv = -1e30f;
    if (l < ctx) {
      float accd = 0.f;
      if (l == ctx - 1) {
        const unsigned short* kn = qkv + (size_t)tq * QKVN + DIMC + h * DC;
        for (int d = 0; d < DC; ++d) accd += sq[d] * bf2f(kn[d]);
      } else {
        int blk = btab[b * MAXBC + (l >> 4)];
        const float* kp = kheap + (((size_t)blk * 16 + (l & 15)) * HC + h) * DC;
#pragma unroll
        for (int d = 0; d < DC; d += 4) {
          f32x4 kv = *(const f32x4*)(kp + d);
          accd += sq[d] * kv[0] + sq[d+1] * kv[1] + sq[d+2] * kv[2] + sq[d+3] * kv[3];
        }
      }
      sv = accd * PSCALE;
    }
    sp[l] = sv;
    lmax = fmaxf(lmax, sv);
  }
  for (int off = 32; off; off >>= 1) lmax = fmaxf(lmax, __shfl_xor(lmax, off));
  if ((tid & 63) == 0) sred[tid >> 6] = lmax;
  __syncthreads();
  const float m = fmaxf(fmaxf(sred[0], sred[1]), fmaxf(sred[2], sred[3]));
  __syncthreads();

  float lsum = 0.f;
#pragma unroll
  for (int i = 0; i < 4; ++i) {
    int l = i * 256 + tid;
    float p = __expf(sp[l] - m);
    sp[l] = p;
    lsum += p;
  }
  for (int off = 32; off; off >>= 1) lsum += __shfl_xor(lsum, off);
  if ((tid & 63) == 0) sred[tid >> 6] = lsum;
  __syncthreads();
  const float denom = sred[0] + sred[1] + sred[2] + sred[3];

  const int d = tid & 127, half = tid >> 7;
  float o = 0.f;
  for (int l = half; l < ctx; l += 2) {
    float p = sp[l];
    float v;
    if (l == ctx - 1) {
      v = bf2f(qkv[(size_t)tq * QKVN + 2 * DIMC + h * DC + d]);
    } else {
      int blk = btab[b * MAXBC + (l >> 4)];
      v = vheap[(((size_t)blk * 16 + (l & 15)) * HC + h) * DC + d];
    }
    o += p * v;
  }
  if (half) obuf[d] = o;
  __syncthreads();
  if (!half)
    attnb[(size_t)tq * DIMC + h * DC + d] = f2bf((o + obuf[d]) / denom);
}

// ---------------- SiLU(g) * u (fallback path only) ----------------
__global__ __launch_bounds__(256) void silu_mul(
    const unsigned short* __restrict__ gu, unsigned short* __restrict__ act)
{
  size_t chunk = (size_t)blockIdx.x * 256 + threadIdx.x;
  size_t row = chunk >> 11;
  int c = (int)(chunk & 2047) << 3;
  const unsigned short* g = gu + row * (2 * FFNC) + c;
  u16x8 gv = *(const u16x8*)g;
  u16x8 uv = *(const u16x8*)(g + FFNC);
  u16x8 o;
#pragma unroll
  for (int i = 0; i < 8; ++i) {
    float gf = bf2f(gv[i]);
    float uf = bf2f(uv[i]);
    float sf = gf / (1.f + __expf(-gf));
    o[i] = f2bf(sf * uf);
  }
  *(u16x8*)(act + row * FFNC + c) = o;
}

// ---------------- launch ----------------
extern "C" void kernel_launch(void* const* d_in, const int* in_sizes, int n_in,
                              void* d_out, int out_size, void* d_ws, size_t ws_size,
                              hipStream_t stream) {
  const float* x     = (const float*)d_in[0];
  const float* kheap = (const float*)d_in[1];
  const float* vheap = (const float*)d_in[2];
  const int*   btab  = (const int*)d_in[4];
  const int*   ctxl  = (const int*)d_in[5];
  const float* n1w   = (const float*)d_in[10];
  const float* n2w   = (const float*)d_in[11];
  const float* wqkv  = (const float*)d_in[12];
  const float* wo    = (const float*)d_in[13];
  const float* wgu   = (const float*)d_in[14];
  const float* w2    = (const float*)d_in[15];
  float* out = (float*)d_out;

  char* ws = (char*)d_ws;
  unsigned short* xn   = (unsigned short*)(ws);
  unsigned short* qkvb = (unsigned short*)(ws + 16842752);
  unsigned short* actb = qkvb;   // alias: qkv dead after wo GEMM
  unsigned short* attn = (unsigned short*)(ws + 16842752 + 67371008);
  float*          hbuf = (float*)(ws + 16842752 + 67371008 + 16842752);
  unsigned short* gub  = (unsigned short*)(ws + 16842752 + 67371008 + 16842752 + 33685504);

  const size_t wbase = 269484032;
  const bool bw = ws_size >= wbase + 536870912ull;
  unsigned short* wqkv_h = (unsigned short*)(ws + wbase);
  unsigned short* wo_h   = (unsigned short*)(ws + wbase + 100663296);
  unsigned short* wgu_h  = (unsigned short*)(ws + wbase + 100663296 + 33554432);  // PERMUTED
  unsigned short* w2_h   = (unsigned short*)(ws + wbase + 100663296 + 33554432 + 268435456);
  const size_t pko = wbase + 536870912ull;
  const bool sk4 = bw && (ws_size >= pko + 134742016ull);
  float* pbuf = (float*)(ws + pko);

  const int nM8 = 9;   // ceil(2056/256)
  const int nM4 = 17;  // ceil(2056/128)
  const long wguN8 = (long)2 * FFNC * DIMC / 8;   // 16,777,216
  const long woN8  = (long)DIMC * DIMC / 8;       //  2,097,152
  const long w2N8  = (long)DIMC * FFNC / 8;       //  8,388,608

  // 1. xn = rmsnorm(x) * n1w
  rmsnorm_k<<<TOKC, 256, 0, stream>>>(x, n1w, xn);

  if (bw) {
    // 2a. standalone cvt: wqkv only (needed by the very next GEMM)
    cvt_w<<<2048, 256, 0, stream>>>(wqkv, wqkv_h, (long)QKVN * DIMC / 8);
    // 2b. qkv GEMM; tail blocks co-convert wgu (PERMUTED) + wo.
    //     tiles = 9*48 = 432; grid 1280 -> 848 cvt blocks.
    gemm8p<2,1><<<1280, 512, 0, stream>>>(
        xn, wqkv_h, nullptr, qkvb, nullptr, TOKC, QKVN, DIMC,
        wgu, wgu_h, wguN8, 1, wo, wo_h, woN8);
    // 3. prefill attention
    prefill_attn<<<dim3(HC, PSEQC / 128, 2), 512, 0, stream>>>(qkvb, attn);
    // 4. decode attention
    decode_attn<<<dim3(HC, BDC), 256, 0, stream>>>(qkvb, kheap, vheap, btab, ctxl, attn);
    // 5. h = attn @ wo^T + x
    gemm_bt<1,1><<<nM4 * (DIMC/128), 256, 0, stream>>>(attn, nullptr, wo_h, hbuf, nullptr, x, TOKC, DIMC, DIMC);
    // 6. xn2 = rmsnorm(h) * n2w
    rmsnorm_k<<<TOKC, 256, 0, stream>>>(hbuf, n2w, xn);
    // 7. act = silu-fused gu GEMM (MODE 4, permuted wgu); tail co-converts w2.
    //    tiles = 9*128 = 1152; grid 1280 -> 128 cvt blocks (fit the tail round).
    gemm8p<4,1><<<1280, 512, 0, stream>>>(
        xn, wgu_h, nullptr, actb, nullptr, TOKC, 2*FFNC, DIMC,
        w2, w2_h, w2N8, 0, nullptr, nullptr, 0);
    // 8. out = act @ w2^T + h
    if (sk4) {
      gemm8p<3,4><<<nM8 * (DIMC/256) * 4, 512, 0, stream>>>(
          actb, w2_h, pbuf, nullptr, nullptr, TOKC, DIMC, FFNC,
          nullptr, nullptr, 0, 0, nullptr, nullptr, 0);
      redk<<<(TOKC * DIMC / 4 + 255) / 256, 256, 0, stream>>>(pbuf, hbuf, out, (long)TOKC * DIMC / 4);
    } else {
      gemm8p<1,1><<<nM8 * (DIMC/256), 512, 0, stream>>>(
          actb, w2_h, out, nullptr, hbuf, TOKC, DIMC, FFNC,
          nullptr, nullptr, 0, 0, nullptr, nullptr, 0);
    }
  } else {
    // f32 fallback path (no bf16 weight workspace)
    gemm_bt<2,0><<<nM4 * (QKVN/128), 256, 0, stream>>>(xn, wqkv, nullptr, nullptr, qkvb, nullptr, TOKC, QKVN, DIMC);
    prefill_attn<<<dim3(HC, PSEQC / 128, 2), 512, 0, stream>>>(qkvb, attn);
    decode_attn<<<dim3(HC, BDC), 256, 0, stream>>>(qkvb, kheap, vheap, btab, ctxl, attn);
    gemm_bt<1,0><<<nM4 * (DIMC/128), 256, 0, stream>>>(attn, wo, nullptr, hbuf, nullptr, x, TOKC, DIMC, DIMC);
    rmsnorm_k<<<TOKC, 256, 0, stream>>>(hbuf, n2w, xn);
    gemm_bt<2,0><<<nM4 * (2*FFNC/128), 256, 0, stream>>>(xn, wgu, nullptr, nullptr, gub, nullptr, TOKC, 2*FFNC, DIMC);
    silu_mul<<<(TOKC * (FFNC / 8)) / 256, 256, 0, stream>>>(gub, actb);
    gemm_bt<1,0><<<nM4 * (DIMC/128), 256, 0, stream>>>(actb, w2, nullptr, out, nullptr, hbuf, TOKC, DIMC, FFNC);
  }
}

// Round 12
// 1858.345 us; speedup vs baseline: 1.0600x; 1.0600x over previous
//
#include <hip/hip_runtime.h>
#include <hip/hip_bf16.h>
#include <stdint.h>

// ---------------- problem constants (fixed by setup_inputs) ----------------
#define DIMC   4096
#define HC     32
#define DC     128
#define TPC    2048      // prefill tokens
#define TOKC   2056      // total tokens
#define BDC    8         // decode batch
#define MAXBC  64        // blocks per decode seq
#define PSEQC  1024      // prefill seq len (2 seqs)
#define QKVN   12288     // 3*H*D
#define FFNC   16384     // 4*DIM
#define PSCALE 0.08838834764831843f  // 1/sqrt(128)

typedef __attribute__((ext_vector_type(8))) short short8;
typedef __attribute__((ext_vector_type(4))) float f32x4;
typedef __attribute__((ext_vector_type(4))) unsigned short u16x4;
typedef __attribute__((ext_vector_type(8))) unsigned short u16x8;

__device__ inline unsigned short f2bf(float f) {   // f32 -> bf16 RNE
  union { float f; unsigned u; } v; v.f = f;
  unsigned r = v.u + 0x7FFFu + ((v.u >> 16) & 1u);
  return (unsigned short)(r >> 16);
}
__device__ inline float bf2f(unsigned short u) {
  union { unsigned u; float f; } v; v.u = ((unsigned)u) << 16;
  return v.f;
}
__device__ inline f32x4 mfma16(short8 a, short8 b, f32x4 c) {
  return __builtin_amdgcn_mfma_f32_16x16x32_bf16(a, b, c, 0, 0, 0);
}
__device__ inline void gload16(const void* g, void* l) {
  __builtin_amdgcn_global_load_lds(
      (const __attribute__((address_space(1))) void*)g,
      (__attribute__((address_space(3))) void*)l, 16, 0, 0);
}

// ---------------- weight convert f32 -> bf16 ----------------
__global__ __launch_bounds__(256) void cvt_w(
    const float* __restrict__ in, unsigned short* __restrict__ out, long n8)
{
  long i = (long)blockIdx.x * 256 + threadIdx.x;
  const long stride = (long)gridDim.x * 256;
  for (; i < n8; i += stride) {
    f32x4 a = ((const f32x4*)in)[2 * i];
    f32x4 b = ((const f32x4*)in)[2 * i + 1];
    u16x8 o;
#pragma unroll
    for (int j = 0; j < 4; ++j) { o[j] = f2bf(a[j]); o[j + 4] = f2bf(b[j]); }
    ((u16x8*)out)[i] = o;
  }
}

// -------- wgu convert with 16-col interleave permutation (validated R11) ----
// out row r2: b=r2>>5, off=r2&31; src row = off<16 ? b*16+off
//                                          : 16384 + b*16 + (off&15)
__global__ __launch_bounds__(256) void cvt_wgu_perm(
    const float* __restrict__ in, unsigned short* __restrict__ out, long n8)
{
  long i = (long)blockIdx.x * 256 + threadIdx.x;
  const long stride = (long)gridDim.x * 256;
  for (; i < n8; i += stride) {
    long r2 = i >> 9, c8 = i & 511;
    long b = r2 >> 5, off = r2 & 31;
    long srcr = (off < 16) ? (b * 16 + off) : (16384 + b * 16 + (off & 15));
    long s8 = srcr * 512 + c8;
    f32x4 a = ((const f32x4*)in)[2 * s8];
    f32x4 b2 = ((const f32x4*)in)[2 * s8 + 1];
    u16x8 o;
#pragma unroll
    for (int j = 0; j < 4; ++j) { o[j] = f2bf(a[j]); o[j + 4] = f2bf(b2[j]); }
    ((u16x8*)out)[i] = o;
  }
}

// ---------------- RMSNorm: f32 in -> bf16 out ----------------
__global__ __launch_bounds__(256) void rmsnorm_k(
    const float* __restrict__ x, const float* __restrict__ w,
    unsigned short* __restrict__ out)
{
  const int row = blockIdx.x;
  const int tid = threadIdx.x;
  const f32x4* xr = (const f32x4*)(x + (size_t)row * DIMC);
  f32x4 v[4];
  float ss = 0.f;
#pragma unroll
  for (int i = 0; i < 4; ++i) {
    v[i] = xr[i * 256 + tid];
    ss += v[i][0]*v[i][0] + v[i][1]*v[i][1] + v[i][2]*v[i][2] + v[i][3]*v[i][3];
  }
  for (int off = 32; off; off >>= 1) ss += __shfl_xor(ss, off);
  __shared__ float sred[4];
  if ((tid & 63) == 0) sred[tid >> 6] = ss;
  __syncthreads();
  const float rms = rsqrtf((sred[0]+sred[1]+sred[2]+sred[3]) * (1.f/DIMC) + 1e-5f);
  const f32x4* wr = (const f32x4*)w;
#pragma unroll
  for (int i = 0; i < 4; ++i) {
    f32x4 wv = wr[i * 256 + tid];
    u16x4 o;
#pragma unroll
    for (int j = 0; j < 4; ++j) o[j] = f2bf(v[i][j] * rms * wv[j]);
    *(u16x4*)(out + (size_t)row * DIMC + (size_t)(i * 256 + tid) * 4) = o;
  }
}

// ============ pipelined 256x256 GEMM (T2+T3+T4+T5), bf16 B ============
// EXACT R8 K-loop schedule (measured best: gu 527us, 52% MfmaUtil, no spill).
// C[M,N] = A_bf16[M,K] @ B_bf16[N,K]^T (+Res).
// MODE 1: f32 out + Res; MODE 2: bf16 out; MODE 3: f32 split-K partial;
// MODE 4: fused SiLU-pair epilogue (B = 16-col-interleaved wgu_perm; frag n=0
//         holds g, n=1 holds u in the SAME lane; writes act[M, N/2] bf16).
//         Validated R11 (absmax 0.09375).
template<int MODE, int SK>
__global__ __launch_bounds__(512, 2) void gemm8p(
    const unsigned short* __restrict__ A, const unsigned short* __restrict__ Bh,
    float* __restrict__ Cf, unsigned short* __restrict__ Cb,
    const float* __restrict__ Res, int M, int N, int K)
{
  __shared__ char ldsc[131072];
  const int tid = threadIdx.x;
  const int lane = tid & 63, wid = tid >> 6;
  const int wr = wid >> 2, wc = wid & 3;
  const int lhi = lane >> 4, llo = lane & 15;

  // bijective XCD chunking over the whole grid, then (ks, bn, bm) M-fast
  const int nM = (M + 255) >> 8;
  const int nN = N >> 8;
  const int nwg = gridDim.x, orig = blockIdx.x;
  const int qq = nwg >> 3, rr = nwg & 7;
  const int xcd = orig & 7, lid = orig >> 3;
  const int wgid = (xcd < rr ? xcd*(qq+1) : rr*(qq+1) + (xcd-rr)*qq) + lid;
  const int tiles = nM * nN;
  const int ks = wgid / tiles;
  const int tile = wgid % tiles;
  const int bm = (tile % nM) << 8;
  const int bn = (tile / nM) << 8;
  const int kLen = K / SK;
  const int k0 = ks * kLen;
  const int NT = kLen >> 6;   // >= 4, even, for all our shapes

  // staging sources: slot s=i*512+tid -> row=s>>3, stored chunk (s&7),
  // holding logical chunk (s&7)^(row&7)  (read-side XOR matches)
  const unsigned short* src[2][2][2];  // [op A/B][half][issue]
#pragma unroll
  for (int i = 0; i < 2; ++i) {
    int s = i * 512 + tid;
    int row = s >> 3;
    int chunk = (s & 7) ^ (row & 7);
#pragma unroll
    for (int h = 0; h < 2; ++h) {
      int ga = bm + h * 128 + row; ga = ga < M ? ga : M - 1;
      src[0][h][i] = A  + (size_t)ga * K + k0 + chunk * 8;
      src[1][h][i] = Bh + (size_t)(bn + h * 128 + row) * K + k0 + chunk * 8;
    }
  }

#define STG(U, OP, H) do { \
    int bb_ = (((U) & 1) << 16) + ((OP) << 15) + ((H) << 14) + (wid << 10); \
    gload16(src[OP][H][0] + ((size_t)(U) << 6), ldsc + bb_); \
    gload16(src[OP][H][1] + ((size_t)(U) << 6), ldsc + bb_ + 8192); \
  } while (0)

#define LDA(PB, HA) do { _Pragma("unroll") for (int m_ = 0; m_ < 4; ++m_) { \
    int row_ = wr*64 + m_*16 + llo; \
    int rb_ = (PB) + ((HA) << 14) + row_*128; int sx_ = (row_ & 7) << 4; \
    ar[m_][0] = *(const short8*)(ldsc + rb_ + ((lhi*16) ^ sx_)); \
    ar[m_][1] = *(const short8*)(ldsc + rb_ + ((64 + lhi*16) ^ sx_)); } } while (0)

#define LDB(PB, HB, DST) do { _Pragma("unroll") for (int n_ = 0; n_ < 2; ++n_) { \
    int row_ = wc*32 + n_*16 + llo; \
    int rb_ = (PB) + 32768 + ((HB) << 14) + row_*128; int sx_ = (row_ & 7) << 4; \
    DST[n_][0] = *(const short8*)(ldsc + rb_ + ((lhi*16) ^ sx_)); \
    DST[n_][1] = *(const short8*)(ldsc + rb_ + ((64 + lhi*16) ^ sx_)); } } while (0)

#define MM(QA, QB, B_) do { __builtin_amdgcn_s_setprio(1); \
    _Pragma("unroll") for (int m_ = 0; m_ < 4; ++m_) \
    _Pragma("unroll") for (int n_ = 0; n_ < 2; ++n_) { \
      acc[QA][QB][m_][n_] = mfma16(ar[m_][0], B_[n_][0], acc[QA][QB][m_][n_]); \
      acc[QA][QB][m_][n_] = mfma16(ar[m_][1], B_[n_][1], acc[QA][QB][m_][n_]); } \
    __builtin_amdgcn_s_setprio(0); } while (0)

#define FEN __builtin_amdgcn_sched_barrier(0)
#define BAR __builtin_amdgcn_s_barrier()
#define VMB(N) do { FEN; asm volatile("s_waitcnt vmcnt(" #N ")" ::: "memory"); \
    BAR; FEN; } while (0)

  f32x4 acc[2][2][4][2] = {};
  short8 ar[4][2], b0[2][2], b1[2][2];

  // prologue: t0 {A0,B0,B1,A1} + t1 {A0,B0,B1} = 14 loads; vmcnt(6) lands
  // all of t0, leaves t1{A0,B0,B1}=6 (steady entry invariant); preload frags.
  STG(0, 0, 0); STG(0, 1, 0); STG(0, 1, 1); STG(0, 0, 1);
  STG(1, 0, 0); STG(1, 1, 0); STG(1, 1, 1);
  VMB(6);
  LDA(0, 0); LDB(0, 0, b0);

  for (int t = 0; t < NT - 2; ++t) {
    const int pb = (t & 1) << 16, pbn = ((t + 1) & 1) << 16;
    // q0
    LDB(pb, 1, b1);
    STG(t + 1, 0, 1);
    MM(0, 0, b0);
    BAR;
    // q1
    STG(t + 2, 0, 0);
    MM(0, 1, b1);
    LDA(pb, 1);            // ar <- A1(t), after MM(0,1) read A0 (reg WAR)
    BAR;
    // q2
    STG(t + 2, 1, 0);
    MM(1, 1, b1);
    VMB(8);                // lands t+1{A0,B0} -> q3 may read them
    // q3
    STG(t + 2, 1, 1);
    MM(1, 0, b0);
    LDA(pbn, 0);           // ar <- A0(t+1)
    LDB(pbn, 0, b0);       // b0 <- B0(t+1)
    VMB(6);                // lands t+1{B1,A1}
  }
  // tile NT-2: no t+2 stages; exact tail waits 4,0
  {
    const int pb = ((NT - 2) & 1) << 16, pbn = ((NT - 1) & 1) << 16;
    LDB(pb, 1, b1);
    STG(NT - 1, 0, 1);
    MM(0, 0, b0);
    BAR;
    MM(0, 1, b1);
    LDA(pb, 1);
    BAR;
    MM(1, 1, b1);
    VMB(4);                // lands (NT-1){A0,B0}
    MM(1, 0, b0);
    LDA(pbn, 0);
    LDB(pbn, 0, b0);
    VMB(0);                // lands (NT-1){B1,A1}
  }
  // tile NT-1: barrier-free drain (no stores pending, all data landed)
  {
    const int pb = ((NT - 1) & 1) << 16;
    LDB(pb, 1, b1);
    MM(0, 0, b0);
    MM(0, 1, b1);
    LDA(pb, 1);
    MM(1, 1, b1);
    MM(1, 0, b0);
  }

  // epilogue: C/D layout col=lane&15, row=(lane>>4)*4+j
  float* Pf = (MODE == 3) ? (Cf + (size_t)ks * M * N) : Cf;
#pragma unroll
  for (int qa = 0; qa < 2; ++qa)
#pragma unroll
  for (int m_ = 0; m_ < 4; ++m_)
#pragma unroll
  for (int j = 0; j < 4; ++j) {
    int row = bm + qa*128 + wr*64 + m_*16 + lhi*4 + j;
    if (row < M) {
      if (MODE == 4) {
        // frag n=0 = g (cols base..base+15), n=1 = u (base+16..base+31),
        // same lane; act col = base/2 + llo, act ld = N/2.
#pragma unroll
        for (int qb = 0; qb < 2; ++qb) {
          int base = bn + qb*128 + wc*32;
          float g = acc[qa][qb][m_][0][j];
          float u = acc[qa][qb][m_][1][j];
          float sv = g / (1.f + __expf(-g)) * u;
          Cb[(size_t)row * (N >> 1) + (base >> 1) + llo] = f2bf(sv);
        }
      } else {
#pragma unroll
        for (int qb = 0; qb < 2; ++qb)
#pragma unroll
        for (int n_ = 0; n_ < 2; ++n_) {
          int col = bn + qb*128 + wc*32 + n_*16 + llo;
          float v = acc[qa][qb][m_][n_][j];
          if (MODE == 1) { v += Res[(size_t)row*N + col]; Pf[(size_t)row*N + col] = v; }
          else if (MODE == 3) { Pf[(size_t)row*N + col] = v; }
          else Cb[(size_t)row*N + col] = f2bf(v);
        }
      }
    }
  }
#undef STG
#undef LDA
#undef LDB
#undef MM
#undef FEN
#undef BAR
#undef VMB
}

// ---------------- split-K reduce: out = p0+p1+p2+p3 + res ----------------
__global__ __launch_bounds__(256) void redk(
    const float* __restrict__ p, const float* __restrict__ res,
    float* __restrict__ out, long n4)
{
  long i = (long)blockIdx.x * 256 + threadIdx.x;
  if (i >= n4) return;
  const f32x4* p4 = (const f32x4*)p;
  f32x4 v = p4[i] + p4[i + n4] + p4[i + 2*n4] + p4[i + 3*n4]
          + ((const f32x4*)res)[i];
  ((f32x4*)out)[i] = v;
}

// ---------------- 128x128 2-barrier GEMM (wo + f32 fallback) -------
template<int MODE, int BF16B>
__global__ __launch_bounds__(256) void gemm_bt(
    const unsigned short* __restrict__ A, const float* __restrict__ Bf,
    const unsigned short* __restrict__ Bh,
    float* __restrict__ Cf, unsigned short* __restrict__ Cb,
    const float* __restrict__ Res, int M, int N, int K)
{
  __shared__ unsigned short la[128 * 64];
  __shared__ unsigned short lb[128 * 64];
  const int tid = threadIdx.x;
  const int lane = tid & 63, wid = tid >> 6;
  const int wr = wid >> 1, wc = wid & 1;
  const int lhi = lane >> 4, llo = lane & 15;

  const int nM = (M + 127) >> 7;
  const int nwg = gridDim.x;
  const int orig = blockIdx.x;
  const int qq = nwg >> 3, rr = nwg & 7;
  const int xcd = orig & 7, lid = orig >> 3;
  const int wgid = (xcd < rr ? xcd * (qq + 1) : rr * (qq + 1) + (xcd - rr) * qq) + lid;
  const int bm = (wgid % nM) * 128;
  const int bn = (wgid / nM) * 128;

  const unsigned short* aSrc[4];
  const unsigned short* bSrcH[4];
  char* aDst[4];
  char* bDst[4];
#pragma unroll
  for (int p = 0; p < 4; ++p) {
    int slot = p * 256 + tid;
    int row = slot >> 3;
    int chunk = (slot & 7) ^ (row & 7);
    int gr = bm + row; gr = gr < M ? gr : M - 1;
    aSrc[p] = A + (size_t)gr * K + chunk * 8;
    aDst[p] = (char*)la + p * 4096 + wid * 1024;
    if (BF16B) {
      bSrcH[p] = Bh + (size_t)(bn + row) * K + chunk * 8;
      bDst[p] = (char*)lb + p * 4096 + wid * 1024;
    }
  }

  f32x4 acc[4][4] = {};

  for (int k0 = 0; k0 < K; k0 += 64) {
#pragma unroll
    for (int p = 0; p < 4; ++p) gload16(aSrc[p] + k0, aDst[p]);
    if (BF16B) {
#pragma unroll
      for (int p = 0; p < 4; ++p) gload16(bSrcH[p] + k0, bDst[p]);
    } else {
#pragma unroll
      for (int p = 0; p < 4; ++p) {
        int idx = p * 256 + tid;
        int row = idx >> 3, c8 = (idx & 7) << 3;
        const float* srcf = Bf + (size_t)(bn + row) * K + k0 + c8;
        f32x4 v0 = *(const f32x4*)srcf;
        f32x4 v1 = *(const f32x4*)(srcf + 4);
        short8 bv;
#pragma unroll
        for (int i = 0; i < 4; ++i) { bv[i] = (short)f2bf(v0[i]); bv[i+4] = (short)f2bf(v1[i]); }
        int byt = (row << 7) + (c8 << 1);
        byt ^= (row & 7) << 4;
        *(short8*)((char*)lb + byt) = bv;
      }
    }
    __syncthreads();
#pragma unroll
    for (int kk = 0; kk < 64; kk += 32) {
      short8 af[4], bfr[4];
#pragma unroll
      for (int m = 0; m < 4; ++m) {
        int row = wr * 64 + m * 16 + llo;
        int byt = (row << 7) + ((kk + lhi * 8) << 1);
        byt ^= (row & 7) << 4;
        af[m] = *(const short8*)((const char*)la + byt);
      }
#pragma unroll
      for (int n = 0; n < 4; ++n) {
        int row = wc * 64 + n * 16 + llo;
        int byt = (row << 7) + ((kk + lhi * 8) << 1);
        byt ^= (row & 7) << 4;
        bfr[n] = *(const short8*)((const char*)lb + byt);
      }
#pragma unroll
      for (int m = 0; m < 4; ++m)
#pragma unroll
        for (int n = 0; n < 4; ++n)
          acc[m][n] = mfma16(af[m], bfr[n], acc[m][n]);
    }
    __syncthreads();
  }

#pragma unroll
  for (int m = 0; m < 4; ++m) {
#pragma unroll
    for (int j = 0; j < 4; ++j) {
      int row = bm + wr * 64 + m * 16 + lhi * 4 + j;
      if (row < M) {
#pragma unroll
        for (int n = 0; n < 4; ++n) {
          int col = bn + wc * 64 + n * 16 + llo;
          float v = acc[m][n][j];
          if (MODE == 1) {
            v += Res[(size_t)row * N + col];
            Cf[(size_t)row * N + col] = v;
          } else {
            Cb[(size_t)row * N + col] = f2bf(v);
          }
        }
      }
    }
  }
}

// ---------------- Prefill flash attention (causal, per-seq) ----------------
// 512 thr = 8 waves x 16 q-rows = 128 q-rows/block.  K staged via
// global_load_lds w/ pre-swizzled source; V^T staged with paired u32 writes;
// waves above the diagonal skip compute (wave-uniform guard).
__global__ __launch_bounds__(512) void prefill_attn(
    const unsigned short* __restrict__ qkv, unsigned short* __restrict__ attnb)
{
  const int h = blockIdx.x, qtb = blockIdx.y, s = blockIdx.z;
  const int seq0 = s * PSEQC;
  const int q0 = qtb * 128;
  const int tid = threadIdx.x;
  const int lane = tid & 63, w = tid >> 6;
  const int lhi = lane >> 4, llo = lane & 15;
  const int qw = q0 + w * 16;          // wave's rows qw..qw+15

  __shared__ unsigned short lk[64 * 128];
  __shared__ unsigned short lvt[128 * 72];
  __shared__ unsigned short lp[8][16 * 72];

  short8 qf[4];
  {
    const unsigned short* qrow =
        qkv + (size_t)(seq0 + qw + llo) * QKVN + h * DC;
#pragma unroll
    for (int kk = 0; kk < 4; ++kk)
      qf[kk] = *(const short8*)(qrow + kk * 32 + lhi * 8);
  }

  float m_r[4], l_r[4];
#pragma unroll
  for (int r = 0; r < 4; ++r) { m_r[r] = -1e30f; l_r[r] = 0.f; }
  f32x4 oacc[8] = {};

  const int ntiles = 2 * qtb + 2;
  for (int t = 0; t < ntiles; ++t) {
    const int j0 = t * 64;
#pragma unroll
    for (int p = 0; p < 2; ++p) {
      int idx = p * 512 + tid;
      int row = idx >> 4, cs = idx & 15;
      int cg = cs ^ (row & 7);
      gload16(qkv + (size_t)(seq0 + j0 + row) * QKVN + DIMC + h * DC + cg * 8,
              (char*)lk + p * 8192 + w * 1024);
    }
    {
      int jp = tid >> 4;            // 0..31
      int c8 = (tid & 15) << 3;
      int j = jp * 2;
      const unsigned short* vrow =
          qkv + (size_t)(seq0 + j0 + j) * QKVN + 2 * DIMC + h * DC + c8;
      short8 v0 = *(const short8*)vrow;
      short8 v1 = *(const short8*)(vrow + QKVN);
#pragma unroll
      for (int i = 0; i < 8; ++i) {
        int d = c8 + i;
        int jj = j ^ (((d >> 3) & 7) << 3);
        unsigned pack = (unsigned)(unsigned short)v0[i]
                      | ((unsigned)(unsigned short)v1[i] << 16);
        *(unsigned*)(lvt + d * 72 + jj) = pack;
      }
    }
    asm volatile("s_waitcnt vmcnt(0)" ::: "memory");
    __syncthreads();

    const bool active = (j0 <= qw + 15);   // wave-uniform
    if (active) {
      f32x4 sfr[4] = {};
#pragma unroll
      for (int n = 0; n < 4; ++n) {
        int row = n * 16 + llo;
#pragma unroll
        for (int kk = 0; kk < 4; ++kk) {
          int col = (kk * 32 + lhi * 8) ^ ((row & 7) << 3);
          short8 kf = *(const short8*)(lk + row * 128 + col);
          sfr[n] = mfma16(qf[kk], kf, sfr[n]);
        }
      }

      const bool diag = (j0 + 63 > qw);
      const int qbase = qw + lhi * 4;
      float pv[4][4];
#pragma unroll
      for (int r = 0; r < 4; ++r) {
        float mx = -1e30f;
#pragma unroll
        for (int n = 0; n < 4; ++n) {
          float sv = sfr[n][r] * PSCALE;
          if (diag && (j0 + n * 16 + llo > qbase + r)) sv = -1e30f;
          pv[n][r] = sv;
          mx = fmaxf(mx, sv);
        }
        for (int off = 8; off; off >>= 1) mx = fmaxf(mx, __shfl_xor(mx, off));
        float mnew = fmaxf(m_r[r], mx);
        float alpha = __expf(m_r[r] - mnew);
        m_r[r] = mnew;
        float rs = 0.f;
#pragma unroll
        for (int n = 0; n < 4; ++n) {
          float p = __expf(pv[n][r] - mnew);
          pv[n][r] = p;
          rs += p;
        }
        for (int off = 8; off; off >>= 1) rs += __shfl_xor(rs, off);
        l_r[r] = l_r[r] * alpha + rs;
#pragma unroll
        for (int f = 0; f < 8; ++f) oacc[f][r] *= alpha;
      }

      unsigned short* lpw = lp[w];
#pragma unroll
      for (int r = 0; r < 4; ++r)
#pragma unroll
        for (int n = 0; n < 4; ++n)
          lpw[(lhi * 4 + r) * 72 + n * 16 + llo] = f2bf(pv[n][r]);

#pragma unroll
      for (int kk = 0; kk < 2; ++kk) {
        short8 pf = *(const short8*)(lpw + llo * 72 + kk * 32 + lhi * 8);
#pragma unroll
        for (int f = 0; f < 8; ++f) {
          int d = f * 16 + llo;
          int jb = kk * 32 + lhi * 8;
          int jj = jb ^ (((d >> 3) & 7) << 3);
          short8 vf = *(const short8*)(lvt + d * 72 + jj);
          oacc[f] = mfma16(pf, vf, oacc[f]);
        }
      }
    }
    __syncthreads();
  }

#pragma unroll
  for (int r = 0; r < 4; ++r) {
    int row = seq0 + qw + lhi * 4 + r;
    float inv = 1.f / l_r[r];
#pragma unroll
    for (int f = 0; f < 8; ++f)
      attnb[(size_t)row * DIMC + h * DC + f * 16 + llo] = f2bf(oacc[f][r] * inv);
  }
}

// ---------------- Decode attention (paged KV, fresh-kv override) ------------
__global__ __launch_bounds__(256) void decode_attn(
    const unsigned short* __restrict__ qkv,
    const float* __restrict__ kheap, const float* __restrict__ vheap,
    const int* __restrict__ btab, const int* __restrict__ ctxl,
    unsigned short* __restrict__ attnb)
{
  const int h = blockIdx.x, b = blockIdx.y;
  const int ctx = ctxl[b];
  const int tq = TPC + b;
  const int tid = threadIdx.x;
  __shared__ float sq[DC];
  __shared__ float sp[1024];
  __shared__ float sred[4];
  __shared__ float obuf[DC];

  const unsigned short* qrow = qkv + (size_t)tq * QKVN + h * DC;
  if (tid < DC) sq[tid] = bf2f(qrow[tid]);
  __syncthreads();

  float lmax = -1e30f;
#pragma unroll
  for (int i = 0; i < 4; ++i) {
    int l = i * 256 + tid;
    float sv = -1e30f;
    if (l < ctx) {
      float accd = 0.f;
      if (l == ctx - 1) {
        const unsigned short* kn = qkv + (size_t)tq * QKVN + DIMC + h * DC;
        for (int d = 0; d < DC; ++d) accd += sq[d] * bf2f(kn[d]);
      } else {
        int blk = btab[b * MAXBC + (l >> 4)];
        const float* kp = kheap + (((size_t)blk * 16 + (l & 15)) * HC + h) * DC;
#pragma unroll
        for (int d = 0; d < DC; d += 4) {
          f32x4 kv = *(const f32x4*)(kp + d);
          accd += sq[d] * kv[0] + sq[d+1] * kv[1] + sq[d+2] * kv[2] + sq[d+3] * kv[3];
        }
      }
      sv = accd * PSCALE;
    }
    sp[l] = sv;
    lmax = fmaxf(lmax, sv);
  }
  for (int off = 32; off; off >>= 1) lmax = fmaxf(lmax, __shfl_xor(lmax, off));
  if ((tid & 63) == 0) sred[tid >> 6] = lmax;
  __syncthreads();
  const float m = fmaxf(fmaxf(sred[0], sred[1]), fmaxf(sred[2], sred[3]));
  __syncthreads();

  float lsum = 0.f;
#pragma unroll
  for (int i = 0; i < 4; ++i) {
    int l = i * 256 + tid;
    float p = __expf(sp[l] - m);
    sp[l] = p;
    lsum += p;
  }
  for (int off = 32; off; off >>= 1) lsum += __shfl_xor(lsum, off);
  if ((tid & 63) == 0) sred[tid >> 6] = lsum;
  __syncthreads();
  const float denom = sred[0] + sred[1] + sred[2] + sred[3];

  const int d = tid & 127, half = tid >> 7;
  float o = 0.f;
  for (int l = half; l < ctx; l += 2) {
    float p = sp[l];
    float v;
    if (l == ctx - 1) {
      v = bf2f(qkv[(size_t)tq * QKVN + 2 * DIMC + h * DC + d]);
    } else {
      int blk = btab[b * MAXBC + (l >> 4)];
      v = vheap[(((size_t)blk * 16 + (l & 15)) * HC + h) * DC + d];
    }
    o += p * v;
  }
  if (half) obuf[d] = o;
  __syncthreads();
  if (!half)
    attnb[(size_t)tq * DIMC + h * DC + d] = f2bf((o + obuf[d]) / denom);
}

// ---------------- SiLU(g) * u (fallback path only) ----------------
__global__ __launch_bounds__(256) void silu_mul(
    const unsigned short* __restrict__ gu, unsigned short* __restrict__ act)
{
  size_t chunk = (size_t)blockIdx.x * 256 + threadIdx.x;
  size_t row = chunk >> 11;
  int c = (int)(chunk & 2047) << 3;
  const unsigned short* g = gu + row * (2 * FFNC) + c;
  u16x8 gv = *(const u16x8*)g;
  u16x8 uv = *(const u16x8*)(g + FFNC);
  u16x8 o;
#pragma unroll
  for (int i = 0; i < 8; ++i) {
    float gf = bf2f(gv[i]);
    float uf = bf2f(uv[i]);
    float sf = gf / (1.f + __expf(-gf));
    o[i] = f2bf(sf * uf);
  }
  *(u16x8*)(act + row * FFNC + c) = o;
}

// ---------------- launch ----------------
extern "C" void kernel_launch(void* const* d_in, const int* in_sizes, int n_in,
                              void* d_out, int out_size, void* d_ws, size_t ws_size,
                              hipStream_t stream) {
  const float* x     = (const float*)d_in[0];
  const float* kheap = (const float*)d_in[1];
  const float* vheap = (const float*)d_in[2];
  const int*   btab  = (const int*)d_in[4];
  const int*   ctxl  = (const int*)d_in[5];
  const float* n1w   = (const float*)d_in[10];
  const float* n2w   = (const float*)d_in[11];
  const float* wqkv  = (const float*)d_in[12];
  const float* wo    = (const float*)d_in[13];
  const float* wgu   = (const float*)d_in[14];
  const float* w2    = (const float*)d_in[15];
  float* out = (float*)d_out;

  char* ws = (char*)d_ws;
  unsigned short* xn   = (unsigned short*)(ws);
  unsigned short* qkvb = (unsigned short*)(ws + 16842752);
  unsigned short* actb = qkvb;   // alias: qkv dead after attention+wo
  unsigned short* attn = (unsigned short*)(ws + 16842752 + 67371008);
  float*          hbuf = (float*)(ws + 16842752 + 67371008 + 16842752);
  unsigned short* gub  = (unsigned short*)(ws + 16842752 + 67371008 + 16842752 + 33685504);

  const size_t wbase = 269484032;
  const bool bw = ws_size >= wbase + 536870912ull;
  unsigned short* wqkv_h = (unsigned short*)(ws + wbase);
  unsigned short* wo_h   = (unsigned short*)(ws + wbase + 100663296);
  unsigned short* wgu_h  = (unsigned short*)(ws + wbase + 100663296 + 33554432);  // PERMUTED
  unsigned short* w2_h   = (unsigned short*)(ws + wbase + 100663296 + 33554432 + 268435456);
  const size_t pko = wbase + 536870912ull;
  const bool sk4 = bw && (ws_size >= pko + 134742016ull);
  float* pbuf = (float*)(ws + pko);

  const int nM8 = 9;   // ceil(2056/256)
  const int nM4 = 17;  // ceil(2056/128)

  if (bw) {
    cvt_w<<<2048, 256, 0, stream>>>(wqkv, wqkv_h, (long)QKVN * DIMC / 8);
    cvt_w<<<2048, 256, 0, stream>>>(wo,   wo_h,   (long)DIMC * DIMC / 8);
    cvt_wgu_perm<<<2048, 256, 0, stream>>>(wgu, wgu_h, (long)2 * FFNC * DIMC / 8);
    cvt_w<<<2048, 256, 0, stream>>>(w2,   w2_h,  (long)DIMC * FFNC / 8);
  }

  // 1. xn = rmsnorm(x) * n1w
  rmsnorm_k<<<TOKC, 256, 0, stream>>>(x, n1w, xn);

  if (bw) {
    // 2. qkv = xn @ wqkv^T (bf16 out)
    gemm8p<2,1><<<nM8 * (QKVN/256), 512, 0, stream>>>(xn, wqkv_h, nullptr, qkvb, nullptr, TOKC, QKVN, DIMC);
    // 3. prefill attention
    prefill_attn<<<dim3(HC, PSEQC / 128, 2), 512, 0, stream>>>(qkvb, attn);
    // 4. decode attention
    decode_attn<<<dim3(HC, BDC), 256, 0, stream>>>(qkvb, kheap, vheap, btab, ctxl, attn);
    // 5. h = attn @ wo^T + x
    gemm_bt<1,1><<<nM4 * (DIMC/128), 256, 0, stream>>>(attn, nullptr, wo_h, hbuf, nullptr, x, TOKC, DIMC, DIMC);
    // 6. xn2 = rmsnorm(h) * n2w
    rmsnorm_k<<<TOKC, 256, 0, stream>>>(hbuf, n2w, xn);
    // 7. act = silu-fused gu GEMM (MODE 4, permuted wgu) -> act[TOK,16384]
    gemm8p<4,1><<<nM8 * (2*FFNC/256), 512, 0, stream>>>(xn, wgu_h, nullptr, actb, nullptr, TOKC, 2*FFNC, DIMC);
    // 8. out = act @ w2^T + h
    if (sk4) {
      gemm8p<3,4><<<nM8 * (DIMC/256) * 4, 512, 0, stream>>>(actb, w2_h, pbuf, nullptr, nullptr, TOKC, DIMC, FFNC);
      redk<<<(TOKC * DIMC / 4 + 255) / 256, 256, 0, stream>>>(pbuf, hbuf, out, (long)TOKC * DIMC / 4);
    } else {
      gemm8p<1,1><<<nM8 * (DIMC/256), 512, 0, stream>>>(actb, w2_h, out, nullptr, hbuf, TOKC, DIMC, FFNC);
    }
  } else {
    // f32 fallback path (no bf16 weight workspace)
    gemm_bt<2,0><<<nM4 * (QKVN/128), 256, 0, stream>>>(xn, wqkv, nullptr, nullptr, qkvb, nullptr, TOKC, QKVN, DIMC);
    prefill_attn<<<dim3(HC, PSEQC / 128, 2), 512, 0, stream>>>(qkvb, attn);
    decode_attn<<<dim3(HC, BDC), 256, 0, stream>>>(qkvb, kheap, vheap, btab, ctxl, attn);
    gemm_bt<1,0><<<nM4 * (DIMC/128), 256, 0, stream>>>(attn, wo, nullptr, hbuf, nullptr, x, TOKC, DIMC, DIMC);
    rmsnorm_k<<<TOKC, 256, 0, stream>>>(hbuf, n2w, xn);
    gemm_bt<2,0><<<nM4 * (2*FFNC/128), 256, 0, stream>>>(xn, wgu, nullptr, nullptr, gub, nullptr, TOKC, 2*FFNC, DIMC);
    silu_mul<<<(TOKC * (FFNC / 8)) / 256, 256, 0, stream>>>(gub, actb);
    gemm_bt<1,0><<<nM4 * (DIMC/128), 256, 0, stream>>>(actb, w2, nullptr, out, nullptr, hbuf, TOKC, DIMC, FFNC);
  }
}